// Round 11
// baseline (606.377 us; speedup 1.0000x reference)
//
#include <hip/hip_runtime.h>
#include <hip/hip_bf16.h>

// Problem constants (match reference)
#define VV 50000
#define EE 100
#define HD 64
#define BB 128
#define TT 512
#define KK 12

typedef unsigned int uint32;
typedef __bf16 bf16x8 __attribute__((ext_vector_type(8)));
typedef float  f32x4  __attribute__((ext_vector_type(4)));
typedef _Float16 half2v __attribute__((ext_vector_type(2)));

// ---------- helpers ----------
__device__ __forceinline__ float bf_lo(unsigned u) { return __uint_as_float(u << 16); }
__device__ __forceinline__ float bf_hi(unsigned u) { return __uint_as_float(u & 0xffff0000u); }
__device__ __forceinline__ float rl_f(float v, int lane) {
    return __uint_as_float(__builtin_amdgcn_readlane(__float_as_uint(v), lane));
}
__device__ __forceinline__ float sigm_f(float x) { return 1.f / (1.f + __expf(-x)); }
__device__ __forceinline__ float tanh_f(float x) {
    float e = __expf(2.f * x);
    return 1.f - 2.f / (e + 1.f);
}
__device__ __forceinline__ unsigned short f2bf(float v) {
    return __builtin_bit_cast(unsigned short, __float2bfloat16(v));
}
__device__ __forceinline__ float fdot2(half2v a, uint32 bbits, float c) {
    half2v bv = __builtin_bit_cast(half2v, bbits);
#if __has_builtin(__builtin_amdgcn_fdot2)
    return __builtin_amdgcn_fdot2(a, bv, c, false);
#else
    return c + (float)a[0] * (float)bv[0] + (float)a[1] * (float)bv[1];
#endif
}
// Barrier that does NOT drain vmcnt (LDS visibility only).
__device__ __forceinline__ void lds_barrier() {
    asm volatile("s_waitcnt lgkmcnt(0)" ::: "memory");
    __builtin_amdgcn_s_barrier();
    asm volatile("" ::: "memory");
}

// ---------- K1: vocab projection as MFMA GEMM, all 8 j-tiles per block ----------
// T14 async-stage: B-tile jb+1 prefetched into registers during jb's MFMA.
#define LDK 136

__global__ __launch_bounds__(256) void k1_mfma(
    const float* __restrict__ emb,
    const float* __restrict__ Wih_f, const float* __restrict__ Wih_b,
    __hip_bfloat16* __restrict__ proj)
{
    __shared__ unsigned short lA[64 * LDK];
    __shared__ unsigned short lB[64 * LDK];

    const int tid = threadIdx.x;
    const int v0  = blockIdx.x * 64;

    for (int i = tid; i < 64 * 20; i += 256) {
        int r = i / 20, c2 = i % 20;
        *(uint32*)&lA[r * LDK + 96 + c2 * 2] = 0u;
        *(uint32*)&lB[r * LDK + 96 + c2 * 2] = 0u;
    }
    {
        const float* asrc = emb + (size_t)v0 * EE;
        const int alim = (VV - v0 < 64 ? VV - v0 : 64) * EE;
        for (int i = tid; i < 64 * EE; i += 256) {
            float v = (i < alim) ? asrc[i] : 0.f;
            lA[(i / EE) * LDK + (i % EE)] = f2bf(v);
        }
    }
    // stage B tile for jb=0 (each thread owns 25 elements: idx = i*256+tid)
    {
        const float* W0 = Wih_f;
        #pragma unroll
        for (int i = 0; i < 25; ++i) {
            int idx = i * 256 + tid;
            lB[(idx / EE) * LDK + (idx % EE)] = f2bf(W0[idx]);
        }
    }
    __syncthreads();

    const int w = tid >> 6, l = tid & 63;
    const int lo16 = l & 15, hi = l >> 4;

    bf16x8 afr[4];
    #pragma unroll
    for (int s = 0; s < 4; ++s)
        afr[s] = *(const bf16x8*)&lA[(w * 16 + lo16) * LDK + s * 32 + hi * 8];

    for (int jb = 0; jb < 8; ++jb) {
        // prefetch next B tile into registers (overlaps MFMA below)
        float nb[25];
        if (jb < 7) {
            const float* Wn = ((jb + 1 < 4) ? Wih_f : Wih_b) + (size_t)((jb + 1) & 3) * 64 * EE;
            #pragma unroll
            for (int i = 0; i < 25; ++i) nb[i] = Wn[i * 256 + tid];
        }

        f32x4 acc[4] = { {0.f,0.f,0.f,0.f}, {0.f,0.f,0.f,0.f},
                         {0.f,0.f,0.f,0.f}, {0.f,0.f,0.f,0.f} };
        #pragma unroll
        for (int s = 0; s < 4; ++s) {
            #pragma unroll
            for (int n = 0; n < 4; ++n) {
                bf16x8 bfr = *(const bf16x8*)&lB[(n * 16 + lo16) * LDK + s * 32 + hi * 8];
                acc[n] = __builtin_amdgcn_mfma_f32_16x16x32_bf16(afr[s], bfr, acc[n], 0, 0, 0);
            }
        }
        #pragma unroll
        for (int n = 0; n < 4; ++n) {
            #pragma unroll
            for (int r = 0; r < 4; ++r) {
                int v = v0 + w * 16 + hi * 4 + r;
                int j = jb * 64 + n * 16 + lo16;
                if (v < VV)
                    proj[(size_t)v * 512 + j] = __float2bfloat16(acc[n][r]);
            }
        }
        if (jb < 7) {
            __syncthreads();               // MFMA reads of lB done
            #pragma unroll
            for (int i = 0; i < 25; ++i) {
                int idx = i * 256 + tid;
                lB[(idx / EE) * LDK + (idx % EE)] = f2bf(nb[i]);
            }
            __syncthreads();
        }
    }
}

// ---------- K2: LSTM recurrence. One block per BATCH, J=2 (both dirs). ----------
// 4 waves; thread tid owns gate-row tid for BOTH directions. Weights f16-packed
// (32 half2/rec/lane -> no register pressure -> no AGPR-ization). h packed via
// DPP-xor1 + cvt_pkrtz; matvec = 32 readlane + 32 v_dot2_f32_f16 per rec.
// ONE lds_barrier per step serves both recurrences: the serial skeleton
// (act-write -> barrier -> LDS-read -> cell), measured ~720-900cy, is paid
// once per step instead of once per recurrence-step.
__global__ __launch_bounds__(256, 1) void k2_lstm(
    const int* __restrict__ sent,
    const __hip_bfloat16* __restrict__ proj,
    const float* __restrict__ Whh_f, const float* __restrict__ Whh_b,
    const float* __restrict__ bih_f, const float* __restrict__ bhh_f,
    const float* __restrict__ bih_b, const float* __restrict__ bhh_b,
    const float* __restrict__ h0, const float* __restrict__ c0,
    __hip_bfloat16* __restrict__ Hbuf)
{
    const int b   = blockIdx.x;
    const int tid = threadIdx.x;
    const int u   = tid & 63;
    const int w   = tid >> 6;             // 0:i 1:f 2:g 3:o

    __shared__ float a_lds[2][2][256];    // [pb][dir][row]

    // pack Whh rows into f16 pairs (both dirs)
    half2v wA[32], wB[32];
    {
        const float* rA = Whh_f + (size_t)tid * HD;
        const float* rB = Whh_b + (size_t)tid * HD;
        #pragma unroll
        for (int p = 0; p < 16; ++p) {
            float4 a4 = reinterpret_cast<const float4*>(rA)[p];
            float4 b4 = reinterpret_cast<const float4*>(rB)[p];
            wA[2*p]   = half2v{(_Float16)a4.x, (_Float16)a4.y};
            wA[2*p+1] = half2v{(_Float16)a4.z, (_Float16)a4.w};
            wB[2*p]   = half2v{(_Float16)b4.x, (_Float16)b4.y};
            wB[2*p+1] = half2v{(_Float16)b4.z, (_Float16)b4.w};
        }
    }
    const float biasA = bih_f[tid] + bhh_f[tid];
    const float biasB = bih_b[tid] + bhh_b[tid];

    float hA = h0[((size_t)0 * BB + b) * HD + u];
    float cA = c0[((size_t)0 * BB + b) * HD + u];
    float hB = h0[((size_t)1 * BB + b) * HD + u];
    float cB = c0[((size_t)1 * BB + b) * HD + u];

    const int* srow = sent + (size_t)b * TT;
    const unsigned short* prj = (const unsigned short*)proj;

    // window-4 prefetch of xp for both dirs (raw bf16 bits for row tid)
    uint32 curA[4], curB[4], nxtA[4], nxtB[4];
    #pragma unroll
    for (int i = 0; i < 4; ++i) {
        curA[i] = prj[(size_t)srow[i] * 512 + tid];                    // d0, t=i
        curB[i] = prj[(size_t)srow[TT - 1 - i] * 512 + 256 + tid];     // d1, t=TT-1-i
    }

    __hip_bfloat16* hpA = Hbuf + ((size_t)0 * BB + b) * 128 + u;             // d0 fwd
    __hip_bfloat16* hpB = Hbuf + ((size_t)(TT - 1) * BB + b) * 128 + 64 + u; // d1 bwd
    const ptrdiff_t hstride = (ptrdiff_t)BB * 128;

    int pb = 0;
    for (int s0 = 0; s0 < TT; s0 += 4) {
        // burst-issue next window's gathers (8 independent loads)
        #pragma unroll
        for (int i = 0; i < 4; ++i) {
            int sn = s0 + 4 + i;
            sn = (sn < TT) ? sn : TT - 1;
            nxtA[i] = prj[(size_t)srow[sn] * 512 + tid];
            nxtB[i] = prj[(size_t)srow[TT - 1 - sn] * 512 + 256 + tid];
        }
        #pragma unroll
        for (int i = 0; i < 4; ++i) {
            // pack (h[2q], h[2q+1]) pairs: DPP xor1 + cvt_pkrtz (even lanes valid)
            int dA = __builtin_amdgcn_update_dpp(0, __float_as_int(hA), 0xB1, 0xF, 0xF, false);
            int dB = __builtin_amdgcn_update_dpp(0, __float_as_int(hB), 0xB1, 0xF, 0xF, false);
            uint32 hbA = __builtin_bit_cast(uint32,
                __builtin_amdgcn_cvt_pkrtz(hA, __int_as_float(dA)));
            uint32 hbB = __builtin_bit_cast(uint32,
                __builtin_amdgcn_cvt_pkrtz(hB, __int_as_float(dB)));

            float aA0 = biasA + bf_lo(curA[i]), aA1 = 0.f;
            float aB0 = biasB + bf_lo(curB[i]), aB1 = 0.f;
            #pragma unroll
            for (int q = 0; q < 32; q += 2) {
                uint32 sA0 = (uint32)__builtin_amdgcn_readlane((int)hbA, 2 * q);
                uint32 sA1 = (uint32)__builtin_amdgcn_readlane((int)hbA, 2 * q + 2);
                uint32 sB0 = (uint32)__builtin_amdgcn_readlane((int)hbB, 2 * q);
                uint32 sB1 = (uint32)__builtin_amdgcn_readlane((int)hbB, 2 * q + 2);
                aA0 = fdot2(wA[q],     sA0, aA0);
                aA1 = fdot2(wA[q + 1], sA1, aA1);
                aB0 = fdot2(wB[q],     sB0, aB0);
                aB1 = fdot2(wB[q + 1], sB1, aB1);
            }
            float gA = aA0 + aA1, gB = aB0 + aB1;

            float actA = (w == 2) ? tanh_f(gA) : sigm_f(gA);
            float actB = (w == 2) ? tanh_f(gB) : sigm_f(gB);
            a_lds[pb][0][tid] = actA;
            a_lds[pb][1][tid] = actB;
            lds_barrier();
            float iA = a_lds[pb][0][u],       fA = a_lds[pb][0][64 + u];
            float ggA = a_lds[pb][0][128 + u], oA = a_lds[pb][0][192 + u];
            float iB = a_lds[pb][1][u],       fB = a_lds[pb][1][64 + u];
            float ggB = a_lds[pb][1][128 + u], oB = a_lds[pb][1][192 + u];
            cA = fA * cA + iA * ggA;  hA = oA * tanh_f(cA);
            cB = fB * cB + iB * ggB;  hB = oB * tanh_f(cB);
            pb ^= 1;

            if (w == 0) *hpA = __float2bfloat16(hA);
            if (w == 1) *hpB = __float2bfloat16(hB);
            hpA += hstride;
            hpB -= hstride;
        }
        #pragma unroll
        for (int i = 0; i < 4; ++i) { curA[i] = nxtA[i]; curB[i] = nxtB[i]; }
    }
}

// ---------- K3: emissions, LDS-staged (coalesced Hbuf read + XOR swizzle) ----------
__global__ __launch_bounds__(128) void k3_emis(
    const __hip_bfloat16* __restrict__ Hbuf,
    const float* __restrict__ W_out, const float* __restrict__ b_out,
    float* __restrict__ emis)
{
    const int t = blockIdx.x;
    const int b = threadIdx.x;
    __shared__ float Wl[KK * 128];                 // 6 KB
    __shared__ unsigned short lh[BB * 128];        // 32 KB
    for (int i = threadIdx.x; i < KK * 128; i += 128) Wl[i] = W_out[i];

    {
        const uint4* src = reinterpret_cast<const uint4*>(Hbuf + (size_t)t * BB * 128);
        #pragma unroll
        for (int i = 0; i < 16; ++i) {
            int e = i * 128 + b;                   // 16B-block index, coalesced read
            uint4 v = src[e];
            int r = e >> 4, s = e & 15;
            *(uint4*)((char*)lh + r * 256 + ((s * 16) ^ ((r & 15) << 4))) = v;
        }
    }
    __syncthreads();

    float acc[KK];
    #pragma unroll
    for (int k = 0; k < KK; ++k) acc[k] = b_out[k];

    #pragma unroll
    for (int s = 0; s < 16; ++s) {
        uint4 hv = *(const uint4*)((const char*)lh + b * 256 + ((s * 16) ^ ((b & 15) << 4)));
        float hf[8];
        hf[0] = bf_lo(hv.x); hf[1] = bf_hi(hv.x);
        hf[2] = bf_lo(hv.y); hf[3] = bf_hi(hv.y);
        hf[4] = bf_lo(hv.z); hf[5] = bf_hi(hv.z);
        hf[6] = bf_lo(hv.w); hf[7] = bf_hi(hv.w);
        #pragma unroll
        for (int k = 0; k < KK; ++k) {
            #pragma unroll
            for (int r = 0; r < 8; ++r)
                acc[k] = fmaf(hf[r], Wl[k * 128 + s * 8 + r], acc[k]);
        }
    }
    float* e = emis + ((size_t)b * TT + t) * KK;
    #pragma unroll
    for (int k = 0; k < KK; k += 4) {
        float4 v = make_float4(acc[k], acc[k+1], acc[k+2], acc[k+3]);
        *reinterpret_cast<float4*>(e + k) = v;
    }
}

// ---------- K4: Viterbi per batch (1 wave). ----------
__global__ __launch_bounds__(64) void k4_viterbi(
    const float* __restrict__ emis, const float* __restrict__ trans,
    float* __restrict__ out)
{
    const int b    = blockIdx.x;
    const int lane = threadIdx.x;
    __shared__ float em_lds[TT * KK];                 // 24 KB
    __shared__ unsigned char bp[(TT - 1) * KK + 4];

    {
        const uint4* e4 = reinterpret_cast<const uint4*>(emis + (size_t)b * TT * KK);
        uint4* l4 = reinterpret_cast<uint4*>(em_lds);
        for (int i = lane; i < TT * KK / 4; i += 64) l4[i] = e4[i];
    }
    __syncthreads();

    const int jj = (lane < KK) ? lane : 0;
    float tc[KK];
    #pragma unroll
    for (int i = 0; i < KK; ++i) tc[i] = trans[i * KK + jj];   // column jj

    float vj = em_lds[jj];
    float sv[KK];
    #pragma unroll
    for (int i = 0; i < KK; ++i) sv[i] = rl_f(vj, i);

    for (int t = 1; t < TT; ++t) {
        float best = sv[0] + tc[0];
        int bi = 0;
        #pragma unroll
        for (int i = 1; i < KK; ++i) {
            float cnd = sv[i] + tc[i];
            bool gt = cnd > best;       // strict > keeps first max (jnp.argmax)
            best = gt ? cnd : best;
            bi   = gt ? i : bi;
        }
        if (lane < KK) bp[(t - 1) * KK + lane] = (unsigned char)bi;
        vj = best + em_lds[t * KK + jj];
        #pragma unroll
        for (int i = 0; i < KK; ++i) sv[i] = rl_f(vj, i);
    }

    float best = sv[0]; int bt = 0;
    #pragma unroll
    for (int i = 1; i < KK; ++i) { if (sv[i] > best) { best = sv[i]; bt = i; } }

    if (lane == 0) {
        out[b] = best;
        float* path = out + BB + (size_t)b * TT;
        int tag = bt;
        path[TT - 1] = (float)tag;
        for (int t = TT - 2; t >= 0; --t) {
            tag = bp[t * KK + tag];
            path[t] = (float)tag;
        }
    }
}

// ---------- launcher ----------
extern "C" void kernel_launch(void* const* d_in, const int* in_sizes, int n_in,
                              void* d_out, int out_size, void* d_ws, size_t ws_size,
                              hipStream_t stream) {
    const int*   sent  = (const int*)  d_in[0];
    const float* emb   = (const float*)d_in[1];
    const float* Wih_f = (const float*)d_in[2];
    const float* Whh_f = (const float*)d_in[3];
    const float* bih_f = (const float*)d_in[4];
    const float* bhh_f = (const float*)d_in[5];
    const float* Wih_b = (const float*)d_in[6];
    const float* Whh_b = (const float*)d_in[7];
    const float* bih_b = (const float*)d_in[8];
    const float* bhh_b = (const float*)d_in[9];
    const float* W_out = (const float*)d_in[10];
    const float* b_out = (const float*)d_in[11];
    const float* trans = (const float*)d_in[12];
    const float* h0    = (const float*)d_in[13];
    const float* c0    = (const float*)d_in[14];
    float* out = (float*)d_out;

    char* ws = (char*)d_ws;
    __hip_bfloat16* proj = (__hip_bfloat16*)ws;                       // V*512*2 B
    size_t off = (((size_t)VV * 512 * 2) + 255) & ~(size_t)255;
    __hip_bfloat16* Hbuf = (__hip_bfloat16*)(ws + off);               // T*B*128*2 B
    off += (((size_t)TT * BB * 128 * 2) + 255) & ~(size_t)255;
    float* emis = (float*)(ws + off);                                 // B*T*12*4 B

    k1_mfma<<<dim3((VV + 63) / 64), 256, 0, stream>>>(emb, Wih_f, Wih_b, proj);
    k2_lstm<<<dim3(BB), 256, 0, stream>>>(sent, proj, Whh_f, Whh_b,
                                          bih_f, bhh_f, bih_b, bhh_b,
                                          h0, c0, Hbuf);
    k3_emis<<<dim3(TT), 128, 0, stream>>>(Hbuf, W_out, b_out, emis);
    k4_viterbi<<<dim3(BB), 64, 0, stream>>>(emis, trans, out);
}